// Round 2
// 139.527 us; speedup vs baseline: 1.0525x; 1.0525x over previous
//
#include <hip/hip_runtime.h>

// Additive attention, factored:
//   scores'[b,q,k] = sum_h (-2 w_h) / (1 + Eq[b,q,h]*Ek[b,k,h]),  Eq=e^{2qp}, Ek=e^{2kp}
// (constant sum_h w_h cancels in softmax). K2 groups 4 h-terms per reciprocal:
//   w0/A+w1/B+w2/C+w3/E = [(w0*B+w1*A)*CE + (w2*E+w3*C)*AB] / (AB*CE)
// -> 14 VALU + 1 rcp per 4 h (vs 8 VALU + 4 rcp): -25% issue, -75% trans-pipe.
// Range safety: A..E in [1, ~2e8] -> D=AB*CE <= ~2e33 < FLT_MAX; N <= ~1e25.
//
// K0: repack Wq/Wk -> W4T[d/4][h] (float4 of W[h][4d..4d+3]) for vectorized proj loads.
// K1: projections + exp. X tile staged in LDS (broadcast reads), W4T float4 loads.
// K2: scores -> S. eq-tile + w2 staged in LDS; 8 q per thread; 4-way rcp grouping;
//     wave-uniform skip of fully-masked 64-k spans (S[k>=len] is never read by K3).
// K3: masked softmax + P@V; 512 thr, 16 k-slices; b fastest-varying for balance.

#define Bb 8
#define Qn 256
#define Kk 1024
#define Dd 256
#define Hh 128
#define DVv 128

__device__ __forceinline__ float fexp2(float x) { return __builtin_amdgcn_exp2f(x); }
__device__ __forceinline__ float frcp(float x)  { return __builtin_amdgcn_rcpf(x); }

// ---------------------------------------------------------------------------
// K0: W [H][D] -> W4T [D/4][H] float4. 64 blocks x 256 threads.
// Writes coalesced (lane = h); reads scattered but total is only 256 KB.
// ---------------------------------------------------------------------------
__global__ __launch_bounds__(256)
void repack_w(const float* __restrict__ Wq, const float* __restrict__ Wk,
              float4* __restrict__ Wq4T, float4* __restrict__ Wk4T)
{
    const int blk = blockIdx.x;
    const float* src = (blk < 32) ? Wq : Wk;
    float4*      dst = (blk < 32) ? Wq4T : Wk4T;
    const int idx = (blk & 31) * 256 + threadIdx.x;   // 8192 float4 per matrix
    const int g = idx >> 7;          // d-group 0..63
    const int h = idx & 127;
    dst[idx] = *(const float4*)(src + (size_t)h * Dd + g * 4);
}

// ---------------------------------------------------------------------------
// K1: EqT[b][h][r] = exp2(2*log2e * X[r]·W[h]). 640 blocks x 512 threads.
// Block = 16 rows x 128 h; thread = 4 rows x 1 h.
// X tile in LDS (16 KB); per-wave LDS reads are same-address broadcasts.
// ---------------------------------------------------------------------------
__global__ __launch_bounds__(512)
void proj_exp_kernel(const float* __restrict__ queries,
                     const float* __restrict__ keys,
                     const float4* __restrict__ Wq4T,
                     const float4* __restrict__ Wk4T,
                     float* __restrict__ EqT,
                     float* __restrict__ EkT)
{
    __shared__ __align__(16) float Xs[16 * 256];     // 16 KB
    const int blk = blockIdx.x;                  // 0..127 queries, 128..639 keys
    const float* X; const float4* W4; float* outT; int RB; int i0;
    if (blk < 128) { X = queries; W4 = Wq4T; outT = EqT; RB = Qn; i0 = blk * 16; }
    else           { X = keys;    W4 = Wk4T; outT = EkT; RB = Kk; i0 = (blk - 128) * 16; }
    const int tid = threadIdx.x;
    const int h   = tid & 127;
    const int r4  = __builtin_amdgcn_readfirstlane(tid >> 7);   // 0..3, wave-uniform

    // stage 16x256 X tile, coalesced float4
    {
        const float4* xsrc = (const float4*)(X + (size_t)i0 * Dd);
#pragma unroll
        for (int s = 0; s < 2; ++s) {
            const int idx = tid + 512 * s;       // 1024 float4
            *(float4*)(Xs + idx * 4) = xsrc[idx];
        }
    }
    __syncthreads();

    float acc[4] = {0.f, 0.f, 0.f, 0.f};
    const float4* wp = W4 + h;                   // stride 128 float4 per group
    const float*  xr = Xs + (r4 * 4) * 256;
#pragma unroll 8
    for (int g = 0; g < 64; ++g) {
        const float4 w = wp[(size_t)g * 128];    // coalesced dwordx4
#pragma unroll
        for (int i = 0; i < 4; ++i) {
            const float4 x = *(const float4*)(xr + i * 256 + g * 4);  // broadcast b128
            acc[i] = fmaf(x.x, w.x, acc[i]);
            acc[i] = fmaf(x.y, w.y, acc[i]);
            acc[i] = fmaf(x.z, w.z, acc[i]);
            acc[i] = fmaf(x.w, w.w, acc[i]);
        }
    }
    const int b    = i0 / RB;                    // 16 | RB, never straddles b
    const int rloc = (i0 % RB) + r4 * 4;
    float4 o;
    o.x = fexp2(acc[0] * 2.885390082f);          // e^{2x} = 2^{2x*log2e}
    o.y = fexp2(acc[1] * 2.885390082f);
    o.z = fexp2(acc[2] * 2.885390082f);
    o.w = fexp2(acc[3] * 2.885390082f);
    *(float4*)(outT + (size_t)b * Hh * RB + (size_t)h * RB + rloc) = o;
}

// ---------------------------------------------------------------------------
// K2: scores -> S[b][q][k]. 1024 blocks (qt<<5 | kt<<3 | b), 256 threads.
// Block = 8 q x 256 k; thread = 8 q x 1 k. eq tile + w2 staged in LDS.
// Masked k-tiles exit immediately; fully-masked 64-k wave spans skip the loop.
// 4-way h-grouping: one v_rcp per 4 h-terms.
// ---------------------------------------------------------------------------
__global__ __launch_bounds__(256)
void score_kernel(const float* __restrict__ EqT,
                  const float* __restrict__ EkT,
                  const float* __restrict__ wv,
                  const int* __restrict__ valid_lens,
                  float* __restrict__ S)
{
    __shared__ __align__(16) float eqs[128 * 8];   // 4 KB  [h][8q]
    __shared__ __align__(16) float w2s[128];
    const int blk = blockIdx.x;
    const int b   = blk & 7;
    const int rem = blk >> 3;
    const int kt  = rem & 3;
    const int qt  = rem >> 2;                   // 0..31
    const int len = valid_lens[b];
    if (kt * 256 >= len) return;                // uniform early-exit

    const int tid = threadIdx.x;
    const int k   = kt * 256 + tid;
    const int q0  = qt * 8;

    {   // stage eq tile: 128 h x 8 q, and -2*wv
        const int hh = tid >> 1, part = tid & 1;
        *(float4*)(eqs + hh * 8 + part * 4) =
            *(const float4*)(EqT + (size_t)b * Hh * Qn + (size_t)hh * Qn + q0 + part * 4);
        if (tid < 128) w2s[tid] = -2.0f * wv[tid];
    }
    __syncthreads();

    // wave-uniform skip: if this wave's whole 64-k span is masked, its S values
    // are never read by K3 (which only touches k < len). Safe after the barrier.
    if ((k & ~63) >= len) return;

    const float* ekp = EkT + (size_t)b * Hh * Kk + k;
    float a[8];
#pragma unroll
    for (int j = 0; j < 8; ++j) a[j] = 0.f;

#pragma unroll 2
    for (int hg = 0; hg < 32; ++hg) {
        const int h = hg << 2;
        const float ek0 = ekp[(size_t)(h + 0) * Kk];   // coalesced global dwords
        const float ek1 = ekp[(size_t)(h + 1) * Kk];
        const float ek2 = ekp[(size_t)(h + 2) * Kk];
        const float ek3 = ekp[(size_t)(h + 3) * Kk];
        const float4 w = *(const float4*)(w2s + h);    // LDS broadcast b128
        float eq[4][8];                                 // fully unrolled -> registers
#pragma unroll
        for (int i = 0; i < 4; ++i) {
            *(float4*)(&eq[i][0]) = *(const float4*)(eqs + (h + i) * 8);
            *(float4*)(&eq[i][4]) = *(const float4*)(eqs + (h + i) * 8 + 4);
        }
#pragma unroll
        for (int j = 0; j < 8; ++j) {
            const float A  = fmaf(eq[0][j], ek0, 1.0f);
            const float B  = fmaf(eq[1][j], ek1, 1.0f);
            const float C  = fmaf(eq[2][j], ek2, 1.0f);
            const float E  = fmaf(eq[3][j], ek3, 1.0f);
            const float AB = A * B;
            const float CE = C * E;
            const float N1 = fmaf(w.x, B, w.y * A);    // (w0*B + w1*A)
            const float N2 = fmaf(w.z, E, w.w * C);    // (w2*E + w3*C)
            const float N  = fmaf(N1, CE, N2 * AB);
            a[j] = fmaf(N, frcp(AB * CE), a[j]);
        }
    }
    float* srow = S + (size_t)(b * Qn + q0) * Kk + k;
#pragma unroll
    for (int j = 0; j < 8; ++j) srow[(size_t)j * Kk] = a[j];   // coalesced
}

// ---------------------------------------------------------------------------
// K3: per (b, 4 q): load scores, masked softmax, P@V.
// 512 blocks (qt<<3 | b) x 512 threads; PV uses 16 k-slices x 32 v-lanes.
// ---------------------------------------------------------------------------
__global__ __launch_bounds__(512)
void softmax_pv_kernel(const float* __restrict__ S,
                       const float* __restrict__ values,
                       const int* __restrict__ valid_lens,
                       float* __restrict__ out)
{
    __shared__ float  s_sc[4][Kk];       // 16 KB
    __shared__ float4 s_part[7][4][32];  // 14 KB
    __shared__ float  s_inv[4];

    const int blk  = blockIdx.x;
    const int b    = blk & 7;
    const int q0   = (blk >> 3) << 2;
    const int tid  = threadIdx.x;
    const int lane = tid & 63;
    const int wave = __builtin_amdgcn_readfirstlane(tid >> 6);
    const int len  = valid_lens[b];

    // ---- load scores (k < len only)
#pragma unroll
    for (int j = 0; j < 4; ++j) {
        const float* sr = S + (size_t)(b * Qn + q0 + j) * Kk;
        for (int k = tid; k < len; k += 512) s_sc[j][k] = sr[k];
    }
    __syncthreads();

    // ---- masked softmax, wave w (<4) owns q = w
    if (wave < 4) {
        const int q = wave;
        float m = -3.0e38f;
        for (int i = lane; i < len; i += 64) m = fmaxf(m, s_sc[q][i]);
#pragma unroll
        for (int off = 32; off > 0; off >>= 1) m = fmaxf(m, __shfl_xor(m, off));
        float sum = 0.f;
        for (int i = lane; i < len; i += 64) {
            const float p = fexp2((s_sc[q][i] - m) * 1.44269504f);
            s_sc[q][i] = p;
            sum += p;
        }
#pragma unroll
        for (int off = 32; off > 0; off >>= 1) sum += __shfl_xor(sum, off);
        if (lane == 0) s_inv[q] = frcp(sum);
    }
    __syncthreads();

    // ---- P@V: 16 k-slices x (32 lanes x float4 = 128 v)
    {
        const int slice = tid >> 5;
        const int l32   = tid & 31;
        const int v4    = l32 << 2;
        const float* vp = values + (size_t)b * Kk * DVv + v4;
        float a[4][4];
#pragma unroll
        for (int q = 0; q < 4; ++q) { a[q][0]=0.f; a[q][1]=0.f; a[q][2]=0.f; a[q][3]=0.f; }
        for (int k = slice; k < len; k += 16) {
            const float4 val = *(const float4*)(vp + (size_t)k * DVv);
            const float w0 = s_sc[0][k], w1 = s_sc[1][k], w2 = s_sc[2][k], w3 = s_sc[3][k];
            a[0][0] = fmaf(w0, val.x, a[0][0]);
            a[0][1] = fmaf(w0, val.y, a[0][1]);
            a[0][2] = fmaf(w0, val.z, a[0][2]);
            a[0][3] = fmaf(w0, val.w, a[0][3]);
            a[1][0] = fmaf(w1, val.x, a[1][0]);
            a[1][1] = fmaf(w1, val.y, a[1][1]);
            a[1][2] = fmaf(w1, val.z, a[1][2]);
            a[1][3] = fmaf(w1, val.w, a[1][3]);
            a[2][0] = fmaf(w2, val.x, a[2][0]);
            a[2][1] = fmaf(w2, val.y, a[2][1]);
            a[2][2] = fmaf(w2, val.z, a[2][2]);
            a[2][3] = fmaf(w2, val.w, a[2][3]);
            a[3][0] = fmaf(w3, val.x, a[3][0]);
            a[3][1] = fmaf(w3, val.y, a[3][1]);
            a[3][2] = fmaf(w3, val.z, a[3][2]);
            a[3][3] = fmaf(w3, val.w, a[3][3]);
        }
        // fold the two slices within each wave
#pragma unroll
        for (int q = 0; q < 4; ++q)
#pragma unroll
            for (int x = 0; x < 4; ++x) a[q][x] += __shfl_xor(a[q][x], 32);
        if (wave > 0 && lane < 32) {
#pragma unroll
            for (int q = 0; q < 4; ++q)
                s_part[wave - 1][q][l32] = make_float4(a[q][0], a[q][1], a[q][2], a[q][3]);
        }
        __syncthreads();
        if (wave == 0 && lane < 32) {
#pragma unroll
            for (int q = 0; q < 4; ++q) {
                float r0 = a[q][0], r1 = a[q][1], r2 = a[q][2], r3 = a[q][3];
#pragma unroll
                for (int w = 0; w < 7; ++w) {
                    const float4 p = s_part[w][q][l32];
                    r0 += p.x; r1 += p.y; r2 += p.z; r3 += p.w;
                }
                const float inv = s_inv[q];
                *(float4*)(out + (size_t)(b * Qn + q0 + q) * DVv + v4) =
                    make_float4(r0 * inv, r1 * inv, r2 * inv, r3 * inv);
            }
        }
    }
}

extern "C" void kernel_launch(void* const* d_in, const int* in_sizes, int n_in,
                              void* d_out, int out_size, void* d_ws, size_t ws_size,
                              hipStream_t stream) {
    (void)in_sizes; (void)n_in; (void)out_size; (void)ws_size;
    const float* queries    = (const float*)d_in[0];
    const float* keys       = (const float*)d_in[1];
    const float* values     = (const float*)d_in[2];
    const int*   valid_lens = (const int*)  d_in[3];
    const float* Wq         = (const float*)d_in[4];
    const float* Wk         = (const float*)d_in[5];
    const float* wvv        = (const float*)d_in[6];
    float* out = (float*)d_out;

    float* Wq4T = (float*)d_ws;                                  // 256*128 floats
    float* Wk4T = Wq4T + (size_t)Dd * Hh;
    float* EqT  = Wk4T + (size_t)Dd * Hh;                        // 8*128*256
    float* EkT  = EqT + (size_t)Bb * Hh * Qn;                    // 8*128*1024
    float* S    = EkT + (size_t)Bb * Hh * Kk;                    // 8*256*1024

    repack_w       <<<  64, 256, 0, stream>>>(Wq, Wk, (float4*)Wq4T, (float4*)Wk4T);
    proj_exp_kernel<<< 640, 512, 0, stream>>>(queries, keys, (const float4*)Wq4T,
                                              (const float4*)Wk4T, EqT, EkT);
    score_kernel   <<<1024, 256, 0, stream>>>(EqT, EkT, wvv, valid_lens, S);
    softmax_pv_kernel<<<512, 512, 0, stream>>>(S, values, valid_lens, out);
}

// Round 3
// 133.544 us; speedup vs baseline: 1.0997x; 1.0448x over previous
//
#include <hip/hip_runtime.h>

// Additive attention, factored:
//   scores'[b,q,k] = sum_h (-2 w_h) / (1 + Eq[b,q,h]*Ek[b,k,h]),  Eq=e^{2qp}, Ek=e^{2kp}
// (constant sum_h w_h cancels in softmax). 4-way reciprocal grouping:
//   w0/A+w1/B+w2/C+w3/E = [(w0*B+w1*A)*CE + (w2*E+w3*C)*AB] / (AB*CE)
// Range safety: A..E in [1, ~2e8] -> AB*CE <= ~2e33 < FLT_MAX.
//
// K0: repack Wq/Wk -> W4T[d/4][h] (float4 of W[h][4d..4d+3]) for vectorized proj loads.
// K1: projections + exp. X tile staged in LDS (broadcast reads), W4T float4 loads.
// K23 (fused): per (b, 4-q tile): scores -> LDS (no S round-trip), in-place masked
//     softmax, P@V. PV partials buffer ALIASED onto the score tile (barrier-guarded).
//     Saves S global write+read, K3's S->LDS staging pass, and one launch.

#define Bb 8
#define Qn 256
#define Kk 1024
#define Dd 256
#define Hh 128
#define DVv 128

__device__ __forceinline__ float fexp2(float x) { return __builtin_amdgcn_exp2f(x); }
__device__ __forceinline__ float frcp(float x)  { return __builtin_amdgcn_rcpf(x); }

// ---------------------------------------------------------------------------
// K0: W [H][D] -> W4T [D/4][H] float4. 64 blocks x 256 threads.
// ---------------------------------------------------------------------------
__global__ __launch_bounds__(256)
void repack_w(const float* __restrict__ Wq, const float* __restrict__ Wk,
              float4* __restrict__ Wq4T, float4* __restrict__ Wk4T)
{
    const int blk = blockIdx.x;
    const float* src = (blk < 32) ? Wq : Wk;
    float4*      dst = (blk < 32) ? Wq4T : Wk4T;
    const int idx = (blk & 31) * 256 + threadIdx.x;   // 8192 float4 per matrix
    const int g = idx >> 7;          // d-group 0..63
    const int h = idx & 127;
    dst[idx] = *(const float4*)(src + (size_t)h * Dd + g * 4);
}

// ---------------------------------------------------------------------------
// K1: EqT[b][h][r] = exp2(2*log2e * X[r]·W[h]). 640 blocks x 512 threads.
// ---------------------------------------------------------------------------
__global__ __launch_bounds__(512)
void proj_exp_kernel(const float* __restrict__ queries,
                     const float* __restrict__ keys,
                     const float4* __restrict__ Wq4T,
                     const float4* __restrict__ Wk4T,
                     float* __restrict__ EqT,
                     float* __restrict__ EkT)
{
    __shared__ __align__(16) float Xs[16 * 256];     // 16 KB
    const int blk = blockIdx.x;                  // 0..127 queries, 128..639 keys
    const float* X; const float4* W4; float* outT; int RB; int i0;
    if (blk < 128) { X = queries; W4 = Wq4T; outT = EqT; RB = Qn; i0 = blk * 16; }
    else           { X = keys;    W4 = Wk4T; outT = EkT; RB = Kk; i0 = (blk - 128) * 16; }
    const int tid = threadIdx.x;
    const int h   = tid & 127;
    const int r4  = __builtin_amdgcn_readfirstlane(tid >> 7);   // 0..3, wave-uniform

    {   // stage 16x256 X tile, coalesced float4
        const float4* xsrc = (const float4*)(X + (size_t)i0 * Dd);
#pragma unroll
        for (int s = 0; s < 2; ++s) {
            const int idx = tid + 512 * s;       // 1024 float4
            *(float4*)(Xs + idx * 4) = xsrc[idx];
        }
    }
    __syncthreads();

    float acc[4] = {0.f, 0.f, 0.f, 0.f};
    const float4* wp = W4 + h;                   // stride 128 float4 per group
    const float*  xr = Xs + (r4 * 4) * 256;
#pragma unroll 8
    for (int g = 0; g < 64; ++g) {
        const float4 w = wp[(size_t)g * 128];    // coalesced dwordx4
#pragma unroll
        for (int i = 0; i < 4; ++i) {
            const float4 x = *(const float4*)(xr + i * 256 + g * 4);  // broadcast b128
            acc[i] = fmaf(x.x, w.x, acc[i]);
            acc[i] = fmaf(x.y, w.y, acc[i]);
            acc[i] = fmaf(x.z, w.z, acc[i]);
            acc[i] = fmaf(x.w, w.w, acc[i]);
        }
    }
    const int b    = i0 / RB;                    // 16 | RB, never straddles b
    const int rloc = (i0 % RB) + r4 * 4;
    float4 o;
    o.x = fexp2(acc[0] * 2.885390082f);          // e^{2x} = 2^{2x*log2e}
    o.y = fexp2(acc[1] * 2.885390082f);
    o.z = fexp2(acc[2] * 2.885390082f);
    o.w = fexp2(acc[3] * 2.885390082f);
    *(float4*)(outT + (size_t)b * Hh * RB + (size_t)h * RB + rloc) = o;
}

// ---------------------------------------------------------------------------
// K23 fused: grid 512 (qt<<3 | b), 512 threads (8 waves).
// Phase 1: scores for 4 q rows x (k < len) into s_sc (LDS), 2 k per thread,
//          4-way rcp grouping, wave-uniform 64-span mask skip.
// Phase 2: masked softmax in-place, wave w (<4) owns q = w.
// Phase 3: P@V, 16 k-slices x 32 v-lanes x float4; partials aliased onto s_sc.
// ---------------------------------------------------------------------------
__global__ __launch_bounds__(512)
void score_softmax_pv_kernel(const float* __restrict__ EqT,
                             const float* __restrict__ EkT,
                             const float* __restrict__ wv,
                             const int* __restrict__ valid_lens,
                             const float* __restrict__ values,
                             float* __restrict__ out)
{
    __shared__ __align__(16) float s_sc[4][Kk];   // 16 KB; aliased as PV partials later
    __shared__ __align__(16) float eqs[Hh * 4];   // 2 KB   [h][4q]
    __shared__ __align__(16) float w2s[Hh];       // 0.5 KB
    __shared__ float s_inv[4];

    const int blk  = blockIdx.x;
    const int b    = blk & 7;
    const int qt   = blk >> 3;                    // 0..63
    const int q0   = qt * 4;
    const int len  = valid_lens[b];
    const int tid  = threadIdx.x;
    const int lane = tid & 63;
    const int wave = __builtin_amdgcn_readfirstlane(tid >> 6);

    // ---- stage eq tile (128 h x 4 q) and -2*wv
    if (tid < 128) {
        *(float4*)(eqs + tid * 4) =
            *(const float4*)(EqT + (size_t)b * Hh * Qn + (size_t)tid * Qn + q0);
    } else if (tid < 256) {
        w2s[tid - 128] = -2.0f * wv[tid - 128];
    }
    __syncthreads();

    // ---- phase 1: scores into LDS
    const float* ekbase = EkT + (size_t)b * Hh * Kk;
#pragma unroll
    for (int kk = 0; kk < 2; ++kk) {
        const int k = tid + kk * 512;
        if ((k & ~63) >= len) continue;           // wave-uniform skip (never read later)
        const float* ekp = ekbase + k;
        float a0 = 0.f, a1 = 0.f, a2 = 0.f, a3 = 0.f;
#pragma unroll 2
        for (int hg = 0; hg < 32; ++hg) {
            const int h = hg << 2;
            const float ek0 = ekp[(size_t)(h + 0) * Kk];   // coalesced global dwords
            const float ek1 = ekp[(size_t)(h + 1) * Kk];
            const float ek2 = ekp[(size_t)(h + 2) * Kk];
            const float ek3 = ekp[(size_t)(h + 3) * Kk];
            const float4 w  = *(const float4*)(w2s + h);   // LDS broadcasts (b128)
            const float4 e0 = *(const float4*)(eqs + (h + 0) * 4);  // [q0..q3] at h+0
            const float4 e1 = *(const float4*)(eqs + (h + 1) * 4);
            const float4 e2 = *(const float4*)(eqs + (h + 2) * 4);
            const float4 e3 = *(const float4*)(eqs + (h + 3) * 4);
            {   // q j=0
                const float A = fmaf(e0.x, ek0, 1.0f), B = fmaf(e1.x, ek1, 1.0f);
                const float C = fmaf(e2.x, ek2, 1.0f), E = fmaf(e3.x, ek3, 1.0f);
                const float AB = A * B, CE = C * E;
                const float N = fmaf(fmaf(w.x, B, w.y * A), CE,
                                     fmaf(w.z, E, w.w * C) * AB);
                a0 = fmaf(N, frcp(AB * CE), a0);
            }
            {   // q j=1
                const float A = fmaf(e0.y, ek0, 1.0f), B = fmaf(e1.y, ek1, 1.0f);
                const float C = fmaf(e2.y, ek2, 1.0f), E = fmaf(e3.y, ek3, 1.0f);
                const float AB = A * B, CE = C * E;
                const float N = fmaf(fmaf(w.x, B, w.y * A), CE,
                                     fmaf(w.z, E, w.w * C) * AB);
                a1 = fmaf(N, frcp(AB * CE), a1);
            }
            {   // q j=2
                const float A = fmaf(e0.z, ek0, 1.0f), B = fmaf(e1.z, ek1, 1.0f);
                const float C = fmaf(e2.z, ek2, 1.0f), E = fmaf(e3.z, ek3, 1.0f);
                const float AB = A * B, CE = C * E;
                const float N = fmaf(fmaf(w.x, B, w.y * A), CE,
                                     fmaf(w.z, E, w.w * C) * AB);
                a2 = fmaf(N, frcp(AB * CE), a2);
            }
            {   // q j=3
                const float A = fmaf(e0.w, ek0, 1.0f), B = fmaf(e1.w, ek1, 1.0f);
                const float C = fmaf(e2.w, ek2, 1.0f), E = fmaf(e3.w, ek3, 1.0f);
                const float AB = A * B, CE = C * E;
                const float N = fmaf(fmaf(w.x, B, w.y * A), CE,
                                     fmaf(w.z, E, w.w * C) * AB);
                a3 = fmaf(N, frcp(AB * CE), a3);
            }
        }
        s_sc[0][k] = a0;                          // stride-1 across lanes: conflict-free
        s_sc[1][k] = a1;
        s_sc[2][k] = a2;
        s_sc[3][k] = a3;
    }
    __syncthreads();

    // ---- phase 2: masked softmax in-place, wave w (<4) owns q = w
    if (wave < 4) {
        const int q = wave;
        float m = -3.0e38f;
        for (int i = lane; i < len; i += 64) m = fmaxf(m, s_sc[q][i]);
#pragma unroll
        for (int off = 32; off > 0; off >>= 1) m = fmaxf(m, __shfl_xor(m, off));
        float sum = 0.f;
        for (int i = lane; i < len; i += 64) {
            const float p = fexp2((s_sc[q][i] - m) * 1.44269504f);
            s_sc[q][i] = p;
            sum += p;
        }
#pragma unroll
        for (int off = 32; off > 0; off >>= 1) sum += __shfl_xor(sum, off);
        if (lane == 0) s_inv[q] = frcp(sum);
    }
    __syncthreads();

    // ---- phase 3: P@V, 16 k-slices x (32 lanes x float4 = 128 v)
    {
        const int slice = tid >> 5;
        const int l32   = tid & 31;
        const int v4    = l32 << 2;
        const float* vp = values + (size_t)b * Kk * DVv + v4;
        float a[4][4];
#pragma unroll
        for (int q = 0; q < 4; ++q) { a[q][0]=0.f; a[q][1]=0.f; a[q][2]=0.f; a[q][3]=0.f; }
        for (int k = slice; k < len; k += 16) {
            const float4 val = *(const float4*)(vp + (size_t)k * DVv);
            const float w0 = s_sc[0][k], w1 = s_sc[1][k], w2 = s_sc[2][k], w3 = s_sc[3][k];
            a[0][0] = fmaf(w0, val.x, a[0][0]);
            a[0][1] = fmaf(w0, val.y, a[0][1]);
            a[0][2] = fmaf(w0, val.z, a[0][2]);
            a[0][3] = fmaf(w0, val.w, a[0][3]);
            a[1][0] = fmaf(w1, val.x, a[1][0]);
            a[1][1] = fmaf(w1, val.y, a[1][1]);
            a[1][2] = fmaf(w1, val.z, a[1][2]);
            a[1][3] = fmaf(w1, val.w, a[1][3]);
            a[2][0] = fmaf(w2, val.x, a[2][0]);
            a[2][1] = fmaf(w2, val.y, a[2][1]);
            a[2][2] = fmaf(w2, val.z, a[2][2]);
            a[2][3] = fmaf(w2, val.w, a[2][3]);
            a[3][0] = fmaf(w3, val.x, a[3][0]);
            a[3][1] = fmaf(w3, val.y, a[3][1]);
            a[3][2] = fmaf(w3, val.z, a[3][2]);
            a[3][3] = fmaf(w3, val.w, a[3][3]);
        }
        // fold the two slices within each wave
#pragma unroll
        for (int q = 0; q < 4; ++q)
#pragma unroll
            for (int x = 0; x < 4; ++x) a[q][x] += __shfl_xor(a[q][x], 32);

        // all s_sc reads complete before aliased partial writes
        __syncthreads();
        float4 (*s_part)[4][32] = (float4 (*)[4][32])(&s_sc[0][0]);   // 14 KB alias
        if (wave > 0 && lane < 32) {
#pragma unroll
            for (int q = 0; q < 4; ++q)
                s_part[wave - 1][q][l32] = make_float4(a[q][0], a[q][1], a[q][2], a[q][3]);
        }
        __syncthreads();
        if (wave == 0 && lane < 32) {
#pragma unroll
            for (int q = 0; q < 4; ++q) {
                float r0 = a[q][0], r1 = a[q][1], r2 = a[q][2], r3 = a[q][3];
#pragma unroll
                for (int w = 0; w < 7; ++w) {
                    const float4 p = s_part[w][q][l32];
                    r0 += p.x; r1 += p.y; r2 += p.z; r3 += p.w;
                }
                const float inv = s_inv[q];
                *(float4*)(out + (size_t)(b * Qn + q0 + q) * DVv + v4) =
                    make_float4(r0 * inv, r1 * inv, r2 * inv, r3 * inv);
            }
        }
    }
}

extern "C" void kernel_launch(void* const* d_in, const int* in_sizes, int n_in,
                              void* d_out, int out_size, void* d_ws, size_t ws_size,
                              hipStream_t stream) {
    (void)in_sizes; (void)n_in; (void)out_size; (void)ws_size;
    const float* queries    = (const float*)d_in[0];
    const float* keys       = (const float*)d_in[1];
    const float* values     = (const float*)d_in[2];
    const int*   valid_lens = (const int*)  d_in[3];
    const float* Wq         = (const float*)d_in[4];
    const float* Wk         = (const float*)d_in[5];
    const float* wvv        = (const float*)d_in[6];
    float* out = (float*)d_out;

    float* Wq4T = (float*)d_ws;                                  // 256*128 floats
    float* Wk4T = Wq4T + (size_t)Dd * Hh;
    float* EqT  = Wk4T + (size_t)Dd * Hh;                        // 8*128*256
    float* EkT  = EqT + (size_t)Bb * Hh * Qn;                    // 8*128*1024

    repack_w       <<<  64, 256, 0, stream>>>(Wq, Wk, (float4*)Wq4T, (float4*)Wk4T);
    proj_exp_kernel<<< 640, 512, 0, stream>>>(queries, keys, (const float4*)Wq4T,
                                              (const float4*)Wk4T, EqT, EkT);
    score_softmax_pv_kernel<<<512, 512, 0, stream>>>(EqT, EkT, wvv, valid_lens,
                                                     values, out);
}